// Round 2
// baseline (75.583 us; speedup 1.0000x reference)
//
#include <hip/hip_runtime.h>

// out[b,u] = prod_f(inputs[b,f] * weight[f,u]) + bias[u]
//          = (prod_f inputs[b,f]) * (prod_f weight[f,u]) + bias[u]
// B=32768, F=32, U=256.
// Two-kernel split: Pw computed once (32KB read) instead of redundantly per
// thread (was 128MB of L1 traffic); main kernel is one-wave-per-row pure
// streaming: 4MB read + 32MB write.

#define F 32
#define U 256
#define B_TOTAL 32768

// ---- kernel 1: Pw[u] = prod_f weight[f,u], one block of 256 threads ----
__global__ __launch_bounds__(256)
void pw_kernel(const float* __restrict__ weight, float* __restrict__ pw) {
  const int u = threadIdx.x;  // 0..255, coalesced across lanes
  float p = 1.0f;
#pragma unroll
  for (int f = 0; f < F; ++f) p *= weight[f * U + u];
  pw[u] = p;
}

// ---- kernel 2: one wave per output row ----
// lanes 0..7 load the 128B input row (float4 each), 6-step shfl_xor butterfly
// broadcasts the row product to all 64 lanes (idle lanes contribute 1.0),
// then one coalesced 1KB store of p*Pw + bias per wave.
__global__ __launch_bounds__(256)
void main_kernel(const float* __restrict__ inp, const float* __restrict__ pw,
                 const float* __restrict__ bias, float* __restrict__ out) {
  const int lane = threadIdx.x & 63;
  const int wave = threadIdx.x >> 6;
  const int row = blockIdx.x * 4 + wave;  // 8192 blocks x 4 waves

  float p = 1.0f;
  if (lane < 8) {
    const float4 x = *(const float4*)(inp + (size_t)row * F + lane * 4);
    p = x.x * x.y * x.z * x.w;
  }
  p *= __shfl_xor(p, 1);
  p *= __shfl_xor(p, 2);
  p *= __shfl_xor(p, 4);
  p *= __shfl_xor(p, 8);
  p *= __shfl_xor(p, 16);
  p *= __shfl_xor(p, 32);

  const float4 w4 = *(const float4*)(pw + lane * 4);    // L1-resident (1KB)
  const float4 b4 = *(const float4*)(bias + lane * 4);  // L1-resident (1KB)
  float4 o;
  o.x = p * w4.x + b4.x;
  o.y = p * w4.y + b4.y;
  o.z = p * w4.z + b4.z;
  o.w = p * w4.w + b4.w;
  *(float4*)(out + (size_t)row * U + lane * 4) = o;
}

extern "C" void kernel_launch(void* const* d_in, const int* in_sizes, int n_in,
                              void* d_out, int out_size, void* d_ws, size_t ws_size,
                              hipStream_t stream) {
  const float* inp    = (const float*)d_in[0];  // [B, F]
  const float* weight = (const float*)d_in[1];  // [F, U]
  // d_in[2] = weight_selector: dead code in the reference, unused
  const float* bias   = (const float*)d_in[3];  // [U]
  float* out = (float*)d_out;                   // [B, U]
  float* pw  = (float*)d_ws;                    // [U] scratch

  pw_kernel<<<1, 256, 0, stream>>>(weight, pw);
  main_kernel<<<B_TOTAL / 4, 256, 0, stream>>>(inp, pw, bias, out);
}

// Round 3
// 72.797 us; speedup vs baseline: 1.0383x; 1.0383x over previous
//
#include <hip/hip_runtime.h>

// out[b,u] = prod_f(inputs[b,f] * weight[f,u]) + bias[u]
//          = (prod_f inputs[b,f]) * (prod_f weight[f,u]) + bias[u]
// B=32768, F=32, U=256.
// Single fused kernel (R2 experiment: falsify launch-overhead hypothesis).
// Per block: Pw via coalesced per-column product into LDS (weight L2-hot),
// 4KB input tile -> LDS tree product -> Pin[32], then 8x coalesced 1KB/wave
// float4 stores. Mandatory traffic: 4MB in + 32MB out (+32MB L2 weight re-read).

#define F 32
#define U 256
#define ROWS_PER_BLOCK 32

__global__ __launch_bounds__(256)
void fused_kernel(const float* __restrict__ inp,
                  const float* __restrict__ weight,
                  const float* __restrict__ bias,
                  float* __restrict__ out) {
  __shared__ float partial[256];            // per-float4 products of input tile
  __shared__ float pin_s[ROWS_PER_BLOCK];   // per-row products
  __shared__ float pw_s[U];                 // per-column weight products

  const int tid = threadIdx.x;
  const int base = blockIdx.x * ROWS_PER_BLOCK;

  // ---- Pw[u]: each thread owns one column; loads coalesced across lanes ----
  {
    float p = 1.0f;
#pragma unroll
    for (int f = 0; f < F; ++f) p *= weight[f * U + tid];
    pw_s[tid] = p;
  }

  // ---- input tile: 32 rows x 32 floats = 4KB, one float4 per thread ----
  {
    const float4 x = *(const float4*)(inp + (size_t)base * F + tid * 4);
    partial[tid] = x.x * x.y * x.z * x.w;
  }
  __syncthreads();

  // ---- row products: 8 partials per row ----
  if (tid < ROWS_PER_BLOCK) {
    float p = 1.0f;
#pragma unroll
    for (int k = 0; k < 8; ++k) p *= partial[tid * 8 + k];
    pin_s[tid] = p;
  }
  __syncthreads();

  // ---- epilogue: wave w stores rows {w, w+4, ..., w+28}, 1KB/wave/step ----
  const int lane = tid & 63;
  const int wave = tid >> 6;
  const float4 w4 = *(const float4*)(&pw_s[lane * 4]);
  const float4 b4 = *(const float4*)(bias + lane * 4);
#pragma unroll
  for (int g = 0; g < 8; ++g) {
    const int r = g * 4 + wave;
    const float p = pin_s[r];  // LDS broadcast
    float4 o;
    o.x = p * w4.x + b4.x;
    o.y = p * w4.y + b4.y;
    o.z = p * w4.z + b4.z;
    o.w = p * w4.w + b4.w;
    *(float4*)(out + (size_t)(base + r) * U + lane * 4) = o;
  }
}

extern "C" void kernel_launch(void* const* d_in, const int* in_sizes, int n_in,
                              void* d_out, int out_size, void* d_ws, size_t ws_size,
                              hipStream_t stream) {
  const float* inp    = (const float*)d_in[0];  // [B, F]
  const float* weight = (const float*)d_in[1];  // [F, U]
  // d_in[2] = weight_selector: dead code in the reference, unused
  const float* bias   = (const float*)d_in[3];  // [U]
  float* out = (float*)d_out;                   // [B, U]

  const int B = in_sizes[0] / F;
  fused_kernel<<<B / ROWS_PER_BLOCK, 256, 0, stream>>>(inp, weight, bias, out);
}